// Round 9
// baseline (3603.431 us; speedup 1.0000x reference)
//
#include <hip/hip_runtime.h>
#include <stdint.h>

#define NPTS 8192
#define NS   2048
#define KNNK 32

typedef unsigned long long u64;
typedef float f32x2 __attribute__((ext_vector_type(2)));

// ============================ FPS =============================
// R4's kernel VERBATIM (empirical best across 5 structural variants:
// R4=1705us vs R5-R8=1867-1944us). One barrier/iter; u64 shfl_xor wave
// reduce; one LDS atomicMax per wave into a 3-deep ring; in-loop store.
// key = (d2bits<<32)|(8191-idx): argmax w/ lowest-index tie-break
// (d2>=0 -> f32 bits order-monotone) == jnp.argmax semantics.
// Exact math: rn ops (contract off), sum order ((x+y)+z).
__global__ __launch_bounds__(512)
void fps_kernel(const float* __restrict__ pts,
                float* __restrict__ out_xyz)
{
#pragma clang fp contract(off)
    const int bt  = blockIdx.x;        // b*4 + t0
    const int tid = threadIdx.x;
    const float* frame = pts + (size_t)bt * NPTS * 6;

    __shared__ float4 p4[NPTS];        // 128 KB coords copy
    __shared__ u64 ring[3];

    f32x2 x2[8], y2[8], z2[8], dd2[8];
#pragma unroll
    for (int j = 0; j < 16; ++j) {
        int n = j * 512 + tid;
        float x = frame[n*6+0], y = frame[n*6+1], z = frame[n*6+2];
        x2[j >> 1][j & 1] = x;
        y2[j >> 1][j & 1] = y;
        z2[j >> 1][j & 1] = z;
        dd2[j >> 1][j & 1] = 3.4028234663852886e38f;
        p4[n] = make_float4(x, y, z, 0.0f);
    }
    if (tid < 3) ring[tid] = 0;
    if (tid == 0) {                    // selection 0 = point 0
        float* ow = out_xyz + (size_t)bt * NS * 3;
        ow[0] = x2[0][0]; ow[1] = y2[0][0]; ow[2] = z2[0][0];
    }
    __syncthreads();
    float sx = p4[0].x, sy = p4[0].y, sz = p4[0].z;

    int r = 1;                         // ring slot for iteration i
    for (int i = 1; i < NS; ++i) {
        // packed update vs previous selection, track local max
        f32x2 sxv = {sx, sx}, syv = {sy, sy}, szv = {sz, sz};
        f32x2 m2 = {0.0f, 0.0f};
#pragma unroll
        for (int q = 0; q < 8; ++q) {
            f32x2 dx = x2[q] - sxv;
            f32x2 dy = y2[q] - syv;
            f32x2 dz = z2[q] - szv;
            f32x2 dd = (dx*dx + dy*dy) + dz*dz;
            f32x2 nd;
            nd[0] = fminf(dd2[q][0], dd[0]);
            nd[1] = fminf(dd2[q][1], dd[1]);
            dd2[q] = nd;
            m2[0] = fmaxf(m2[0], nd[0]);
            m2[1] = fmaxf(m2[1], nd[1]);
        }
        float mloc = fmaxf(m2[0], m2[1]);
        // lowest local index holding mloc (descending pass -> first match)
        int bestn = 0;
#pragma unroll
        for (int j = 15; j >= 0; --j)
            bestn = (dd2[j >> 1][j & 1] == mloc) ? (j * 512 + tid) : bestn;
        u64 key = ((u64)__float_as_uint(mloc) << 32) | (unsigned)(8191 - bestn);
        // wave reduce (max key)
#pragma unroll
        for (int off = 32; off > 0; off >>= 1) {
            u64 o = __shfl_xor(key, off, 64);
            key = (o > key) ? o : key;
        }
        if ((tid & 63) == 0) atomicMax(&ring[r], key);
        int rn = r + 1; if (rn == 3) rn = 0;
        if (tid == 0) ring[rn] = 0;    // reset future slot (read 2 iters away)
        __syncthreads();
        u64 k = ring[r];
        int idx = 8191 - (int)(k & 0xFFFFFFFFu);
        float4 c = p4[idx];            // broadcast ds_read_b128
        sx = c.x; sy = c.y; sz = c.z;
        if (tid == 0) {
            float* ow = out_xyz + ((size_t)bt * NS + i) * 3;
            ow[0] = sx; ow[1] = sy; ow[2] = sz;
        }
        r = rn;
    }
}

// ============================ KNN =============================
// 2 waves/block (128 thr): wave w owns candidates [w*4096,(w+1)*4096) for
// the block's 64 anchors (one per lane). Per-wave LDS state: sorted main
// top-32 (rows 0..31) + 32-entry append buffer (rows 32..63), interleaved
// columns; shared trash row. Fast path branchless: 1 f32 cmp
// p = !(d2 > rk_f) (NaN-safe; boundary ties admitted then evicted by the
// full-u64 compaction -> exact set). Compaction unchanged from R6
// (threshold 24, capacity 32). Barriers only at tile boundaries (uniform
// count across both waves; compaction is wave-local).
// Final: min(st0[i], st1[31-i]) = exact union top-32 set (bitonic lower
// half; downstream max-pool is order-insensitive). Tie semantics = jax
// top_k (lexicographic (d2bits, idx) in the u64 keys).
__device__ __forceinline__ void knn_compact(u64* st, int lane, int& cnt, float& rk_f)
{
    for (int e = 0; e < 32; ++e)
        if (e >= cnt) st[(e + 32) * 64 + lane] = ~0ull;
    for (int k = 2; k <= 32; k <<= 1)
        for (int j = k >> 1; j > 0; j >>= 1)
            for (int i = 0; i < 32; ++i) {
                int l = i ^ j;
                if (l > i) {
                    u64 a = st[(i + 32) * 64 + lane];
                    u64 b = st[(l + 32) * 64 + lane];
                    bool asc = ((i & k) == 0);
                    if ((a > b) == asc) {
                        st[(i + 32) * 64 + lane] = b;
                        st[(l + 32) * 64 + lane] = a;
                    }
                }
            }
    for (int i = 0; i < 32; ++i) {
        u64 a = st[i * 64 + lane];
        u64 b = st[(63 - i) * 64 + lane];
        if (b < a) st[i * 64 + lane] = b;
    }
    for (int j = 16; j > 0; j >>= 1)
        for (int i = 0; i < 32; ++i) {
            int l = i ^ j;
            if (l > i) {
                u64 a = st[i * 64 + lane];
                u64 b = st[l * 64 + lane];
                if (a > b) {
                    st[i * 64 + lane] = b;
                    st[l * 64 + lane] = a;
                }
            }
        }
    rk_f = __uint_as_float((unsigned)(st[31 * 64 + lane] >> 32));
    cnt = 0;
}

__global__ __launch_bounds__(128)
void knn_kernel(const float* __restrict__ pts,
                const float* __restrict__ anchors,
                unsigned short* __restrict__ knn_out)
{
    const int blk  = blockIdx.x;       // 8bt * 3di * 32 sblk
    const int bt   = blk / 96;
    const int rr   = blk % 96;
    const int di   = rr / 32;
    const int sblk = rr % 32;
    const int b = bt >> 2, t0 = bt & 3;
    int lnb = t0 + di - 1; lnb = lnb < 0 ? 0 : (lnb > 3 ? 3 : lnb);
    const float* nb = pts + (size_t)(b * 4 + lnb) * NPTS * 6;
    const int tid  = threadIdx.x;
    const int w    = tid >> 6;         // wave: candidate half owner
    const int lane = tid & 63;
    const int s    = sblk * 64 + lane;

    const float* ap = anchors + ((size_t)bt * NS + s) * 3;
    float ax = ap[0], ay = ap[1], az = ap[2];

    __shared__ u64 st[2][64 * 64];     // 64 KB (per-wave main+buffer)
    __shared__ u64 trash[64];          // shared scrap row
    __shared__ float4 tile[2][256];    // 8 KB (per-wave tile)
    u64* stw = st[w];

    for (int e = 0; e < 64; ++e) stw[e * 64 + lane] = ~0ull;
    float rk_f = __uint_as_float(0xFFFFFFFFu);  // NaN -> always insert
    int cnt = 0;

    const int cbase = w * 4096;
    for (int tb = 0; tb < 16; ++tb) {
        __syncthreads();
#pragma unroll
        for (int q = 0; q < 4; ++q) {
            int c = q * 64 + lane;
            int n = cbase + tb * 256 + c;
            tile[w][c] = make_float4(nb[n*6+0], nb[n*6+1], nb[n*6+2], 0.0f);
        }
        __syncthreads();
        for (int c0 = 0; c0 < 256; c0 += 8) {
#pragma unroll
            for (int j = 0; j < 8; ++j) {
                float4 qv = tile[w][c0 + j];
                float dx = __fsub_rn(ax, qv.x);
                float dy = __fsub_rn(ay, qv.y);
                float dz = __fsub_rn(az, qv.z);
                float d2 = __fadd_rn(__fadd_rn(__fmul_rn(dx,dx), __fmul_rn(dy,dy)),
                                     __fmul_rn(dz,dz));
                u64 key = ((u64)__float_as_uint(d2) << 32)
                        | (unsigned)(cbase + tb * 256 + c0 + j);
                bool p = !(d2 > rk_f);
                u64* dst = p ? &stw[(32 + cnt) * 64 + lane] : &trash[lane];
                *dst = key;
                cnt += p ? 1 : 0;
            }
            if (__any(cnt >= 24)) knn_compact(stw, lane, cnt, rk_f);
        }
    }
    knn_compact(stw, lane, cnt, rk_f);
    __syncthreads();

    if (w == 0) {
        unsigned short* op = knn_out + (((size_t)bt * 3 + di) * NS + s) * KNNK;
#pragma unroll
        for (int e = 0; e < 32; ++e) {
            u64 a = st[0][e * 64 + lane];
            u64 c = st[1][(31 - e) * 64 + lane];
            u64 m = c < a ? c : a;     // lower half of bitonic 64-seq
            op[e] = (unsigned short)(m & 0xFFFFull);
        }
    }
}

// ============================ MLP =============================
// LDS-b128-throughput bound (validated: 6 b128/64 FMA * 12cy/b128/CU
// predicted 368us vs ~350 measured). New tiling: 4 anchors/block,
// thread tile 8p x 8k -> 4 b128/64 FMA -> predicted ~245us.
// LDS 75KB -> 2 blocks/CU (8 waves). f32 fmaf, same o-order as before.
__global__ __launch_bounds__(256)
void mlp_kernel(const float* __restrict__ pts,
                const float* __restrict__ anchors,
                const unsigned short* __restrict__ knn,
                const float* __restrict__ Wd,
                const float* __restrict__ Wm,
                float* __restrict__ out_feats)
{
    const int blk = blockIdx.x;
    const int bt  = blk >> 9;          // 512 squads of 4 anchors
    const int sq  = blk & 511;
    const int b = bt >> 2, t0 = bt & 3;
    const int tid = threadIdx.x;
    const int a   = tid >> 6;          // local anchor 0..3
    const int r   = tid & 63;
    const int p0  = (r & 15) * 8;      // 8 consecutive output channels
    const int kt  = r >> 4;            // k-group 0..3
    const int k0  = kt * 8;
    const int s   = sq * 4 + a;

    __shared__ float WmT[64 * 128];    // 32 KB, [o][p]
    __shared__ float Wds[256];         // [o][c]
    __shared__ float h1[4][64][32];    // 32 KB
    __shared__ float d4s[4][32][4];    // 2 KB
    __shared__ float pmax[4][4][128];  // 8 KB, [a][kt][p]

    for (int i = tid; i < 8192; i += 256) {
        int pp = i >> 6, oo = i & 63;
        WmT[oo * 128 + pp] = Wm[i];
    }
    Wds[tid] = Wd[tid];

    float fsum0 = 0.0f, fsum1 = 0.0f;

    for (int dd = 0; dd < 3; ++dd) {
        __syncthreads();   // protect d4s/h1/pmax reuse (and WmT/Wds on dd=0)
        if (tid < 128) {
            int sa = tid >> 5, k = tid & 31;
            int ss = sq * 4 + sa;
            int lnb = t0 + dd - 1; lnb = lnb < 0 ? 0 : (lnb > 3 ? 3 : lnb);
            const float* nbf = pts + (size_t)(b*4 + lnb) * NPTS * 6;
            const float* ap = anchors + ((size_t)bt * NS + ss) * 3;
            int idx = knn[(((size_t)bt*3 + dd) * NS + ss) * KNNK + k];
            d4s[sa][k][0] = nbf[idx*6+0] - ap[0];
            d4s[sa][k][1] = nbf[idx*6+1] - ap[1];
            d4s[sa][k][2] = nbf[idx*6+2] - ap[2];
            d4s[sa][k][3] = (float)(dd - 1);
        }
        __syncthreads();
        // phase 1: h1[a][o][k]; per anchor 64 threads = (k 0..31) x (oh 0..1)
        {
            int k  = r & 31;
            int oh = r >> 5;
            float4 dv = *(const float4*)&d4s[a][k][0];
#pragma unroll
            for (int ii = 0; ii < 32; ++ii) {
                int o = oh * 32 + ii;
                float4 wv = *(const float4*)&Wds[o * 4];
                float h = fmaf(dv.x, wv.x, fmaf(dv.y, wv.y,
                             fmaf(dv.z, wv.z, dv.w * wv.w)));
                h1[a][o][k] = fmaxf(h, 0.0f);
            }
        }
        __syncthreads();
        // phase 2: 8p x 8k register tile; 4 b128 per o for 64 FMA
        float acc[8][8];
#pragma unroll
        for (int i = 0; i < 8; ++i)
#pragma unroll
            for (int j = 0; j < 8; ++j) acc[i][j] = 0.0f;
        for (int o = 0; o < 64; ++o) {
            float4 wv0 = *(const float4*)&WmT[o * 128 + p0];
            float4 wv1 = *(const float4*)&WmT[o * 128 + p0 + 4];
            float4 h0 = *(const float4*)&h1[a][o][k0];
            float4 h4 = *(const float4*)&h1[a][o][k0 + 4];
            float hw[8] = {h0.x, h0.y, h0.z, h0.w, h4.x, h4.y, h4.z, h4.w};
#pragma unroll
            for (int i = 0; i < 8; ++i) {
                float ww = (i < 4) ? ((i == 0) ? wv0.x : (i == 1) ? wv0.y :
                                      (i == 2) ? wv0.z : wv0.w)
                                   : ((i == 4) ? wv1.x : (i == 5) ? wv1.y :
                                      (i == 6) ? wv1.z : wv1.w);
#pragma unroll
                for (int j = 0; j < 8; ++j)
                    acc[i][j] = fmaf(ww, hw[j], acc[i][j]);
            }
        }
        // per-p max over this thread's 8 k's -> pmax
        float4 pmA, pmB;
#pragma unroll
        for (int i = 0; i < 8; ++i) {
            float m = acc[i][0];
#pragma unroll
            for (int j = 1; j < 8; ++j) m = fmaxf(m, acc[i][j]);
            if (i < 4) ((float*)&pmA)[i] = m;
            else       ((float*)&pmB)[i - 4] = m;
        }
        *(float4*)&pmax[a][kt][p0]     = pmA;
        *(float4*)&pmax[a][kt][p0 + 4] = pmB;
        __syncthreads();
        // final: thread (a, r) reduces p = r and p = r+64 over 4 kt
        float m0 = fmaxf(fmaxf(pmax[a][0][r], pmax[a][1][r]),
                         fmaxf(pmax[a][2][r], pmax[a][3][r]));
        float m1 = fmaxf(fmaxf(pmax[a][0][r + 64], pmax[a][1][r + 64]),
                         fmaxf(pmax[a][2][r + 64], pmax[a][3][r + 64]));
        fsum0 += fmaxf(m0, 0.0f);      // max_k relu(x) == relu(max_k x)
        fsum1 += fmaxf(m1, 0.0f);
    }
    out_feats[((size_t)bt * 128 + r) * NS + s]        = fsum0;
    out_feats[((size_t)bt * 128 + r + 64) * NS + s]   = fsum1;
}

// ========================== launcher ==========================
extern "C" void kernel_launch(void* const* d_in, const int* in_sizes, int n_in,
                              void* d_out, int out_size, void* d_ws, size_t ws_size,
                              hipStream_t stream)
{
    const float* pts = (const float*)d_in[0];   // [2,4,8192,6]
    const float* Wd  = (const float*)d_in[1];   // [64,4]
    const float* Wm  = (const float*)d_in[2];   // [128,64]

    float* out_xyz   = (float*)d_out;                 // [2,4,2048,3] == anchors
    float* out_feats = out_xyz + 8 * NS * 3;          // [2,4,128,2048]

    unsigned short* knn = (unsigned short*)d_ws;      // 8*3*2048*32 u16

    fps_kernel<<<8, 512, 0, stream>>>(pts, out_xyz);
    knn_kernel<<<8 * 3 * 32, 128, 0, stream>>>(pts, out_xyz, knn);
    mlp_kernel<<<8 * (NS / 4), 256, 0, stream>>>(pts, out_xyz, knn, Wd, Wm, out_feats);
}